// Round 3
// baseline (863.448 us; speedup 1.0000x reference)
//
#include <hip/hip_runtime.h>

#define T_DIM 512
#define B_DIM 64
#define I_DIM 1024
#define H_DIM 1024
#define G3    3072                 // 3*H
#define M_DIM (T_DIM * B_DIM)      // 32768
#define K_DIM 1024
#define KT    16                   // K_DIM / 64

typedef unsigned short u16;
typedef __bf16 bf16x8 __attribute__((ext_vector_type(8)));
typedef float  f32x4  __attribute__((ext_vector_type(4)));
typedef unsigned short u16x8 __attribute__((ext_vector_type(8)));

__device__ __forceinline__ u16 f2bf(float x) {
  union { float f; unsigned u; } v; v.f = x;
  unsigned r = v.u + 0x7fffu + ((v.u >> 16) & 1u);   // RNE
  return (u16)(r >> 16);
}
__device__ __forceinline__ float bf2f(u16 x) {
  union { unsigned u; float f; } v; v.u = ((unsigned)x) << 16;
  return v.f;
}

// ---------------- cast x: f32 -> bf16, 8 elems/thread ----------------
__global__ void cast_f32_to_bf16_kernel(const float* __restrict__ in,
                                        u16* __restrict__ out, int n8) {
  int idx = blockIdx.x * blockDim.x + threadIdx.x;
  int stride = gridDim.x * blockDim.x;
  for (int i = idx; i < n8; i += stride) {
    const float4* p = (const float4*)in + 2 * (size_t)i;
    float4 a = p[0], b = p[1];
    u16x8 o;
    o[0] = f2bf(a.x); o[1] = f2bf(a.y); o[2] = f2bf(a.z); o[3] = f2bf(a.w);
    o[4] = f2bf(b.x); o[5] = f2bf(b.y); o[6] = f2bf(b.z); o[7] = f2bf(b.w);
    *((u16x8*)out + i) = o;
  }
}

// ------------- transpose-cast W[K][N] f32 -> Wt[N][K] bf16 -------------
__global__ void transpose_cast_kernel(const float* __restrict__ W,
                                      u16* __restrict__ Wt, int K, int N) {
  __shared__ float tile[32][33];
  int n0 = blockIdx.x * 32, k0 = blockIdx.y * 32;
  int tx = threadIdx.x, ty = threadIdx.y;   // blockDim = (32,8)
  #pragma unroll
  for (int dy = 0; dy < 32; dy += 8)
    tile[ty + dy][tx] = W[(size_t)(k0 + ty + dy) * N + n0 + tx];
  __syncthreads();
  #pragma unroll
  for (int dy = 0; dy < 32; dy += 8)
    Wt[(size_t)(n0 + ty + dy) * K + k0 + tx] = f2bf(tile[tx][ty + dy]);
}

// ============ 256x256 GEMM, 1-barrier/K-tile, full-tile prefetch ============
// 8 waves (2M x 4N), BK=64, 2 LDS K-tile buffers. Per tile: vmcnt(0) on loads
// issued ONE FULL TILE ago (cheap), barrier, issue ALL of tile T+1 (safe: the
// barrier proves every wave consumed tile T-1 from that buffer), then 24
// ds_read_b128 + 64 MFMA compiler-scheduled with fine lgkmcnt. T2 source-side
// XOR swizzle keeps ds_read conflict-free (verified 0 conflicts in R2).
__device__ __forceinline__ void gload_lds16(const void* g, void* l) {
  __builtin_amdgcn_global_load_lds(
      (const __attribute__((address_space(1))) void*)g,
      (__attribute__((address_space(3))) void*)l, 16, 0, 0);
}

// stage one half-tile (128 rows x 64 k) of operand G (row stride K_DIM), rows
// [rb, rb+128) at k0 into lbuf (linear [256][64] u16). Source pre-swizzled so a
// read-side XOR (slot = chunk ^ (row&7)) sees logical data (rule 21 pattern).
__device__ __forceinline__ void stage_half(const u16* __restrict__ G, u16* lbuf,
                                           int rb, int k0, int w, int l) {
  const int cs   = (l & 7) ^ (l >> 3);   // source chunk for this lane
  const int rsub = l >> 3;
  #pragma unroll
  for (int r = 0; r < 2; ++r) {
    const int row0 = rb + r * 64 + w * 8;           // wave-uniform row base (mult of 8)
    gload_lds16(G + (size_t)(row0 + rsub) * K_DIM + k0 + cs * 8,
                lbuf + (size_t)row0 * 64);
  }
}

// read one MFMA fragment; row must be (mult of 16) + fr so row&7 == fr&7
__device__ __forceinline__ bf16x8 ldfrag(const u16* buf, int row, int ks, int fr, int g4) {
  const int slot = ((ks << 2) + g4) ^ (fr & 7);
  return *(const bf16x8*)(buf + (size_t)row * 64 + slot * 8);
}

__global__ __launch_bounds__(512, 2) void gemm256_kernel(
    const u16* __restrict__ A, const u16* __restrict__ Bt,
    const float* __restrict__ bias, u16* __restrict__ C, int N) {
  __shared__ u16 As[2][256 * 64];
  __shared__ u16 Bs[2][256 * 64];
  const int tid = threadIdx.x;
  const int l  = tid & 63, w = tid >> 6;
  const int wm = w >> 2,  wn = w & 3;
  const int fr = l & 15,  g4 = l >> 4;

  // T1: bijective XCD swizzle (nwg = 1536, divisible by 8)
  const int lin = blockIdx.y * gridDim.x + blockIdx.x;
  const int cpx = (gridDim.x * gridDim.y) >> 3;
  const int swz = (lin & 7) * cpx + (lin >> 3);
  const int bx = swz % gridDim.x, by = swz / gridDim.x;
  const int bm = by * 256, bn = bx * 256;

  const u16* Ab = A  + (size_t)bm * K_DIM;
  const u16* Bb = Bt + (size_t)bn * K_DIM;

  // prologue: tile 0 -> buf 0 (8 loads/thread)
  stage_half(Ab, As[0], 0,   0, w, l);
  stage_half(Ab, As[0], 128, 0, w, l);
  stage_half(Bb, Bs[0], 0,   0, w, l);
  stage_half(Bb, Bs[0], 128, 0, w, l);

  f32x4 acc[8][4] = {};

  #pragma unroll 2
  for (int T = 0; T < KT; ++T) {
    const u16* Ac = As[T & 1];
    const u16* Bc = Bs[T & 1];

    // tile T's loads were issued one full tile ago -> this drain is cheap
    asm volatile("s_waitcnt vmcnt(0)" ::: "memory");
    __builtin_amdgcn_s_barrier();          // tile T LDS complete everywhere;
                                           // tile T-1 reads all consumed
    __builtin_amdgcn_sched_barrier(0);

    if (T + 1 < KT) {                      // issue ALL of tile T+1 now
      u16* An = As[(T + 1) & 1];
      u16* Bn = Bs[(T + 1) & 1];
      const int k1 = (T + 1) * 64;
      stage_half(Ab, An, 0,   k1, w, l);
      stage_half(Ab, An, 128, k1, w, l);
      stage_half(Bb, Bn, 0,   k1, w, l);
      stage_half(Bb, Bn, 128, k1, w, l);
    }
    __builtin_amdgcn_sched_barrier(0);     // keep stage issue ahead of compute

    bf16x8 av[8][2], bv[4][2];
    #pragma unroll
    for (int m = 0; m < 8; ++m) {
      av[m][0] = ldfrag(Ac, wm * 128 + m * 16 + fr, 0, fr, g4);
      av[m][1] = ldfrag(Ac, wm * 128 + m * 16 + fr, 1, fr, g4);
    }
    #pragma unroll
    for (int n = 0; n < 4; ++n) {
      bv[n][0] = ldfrag(Bc, wn * 64 + n * 16 + fr, 0, fr, g4);
      bv[n][1] = ldfrag(Bc, wn * 64 + n * 16 + fr, 1, fr, g4);
    }
    __builtin_amdgcn_s_setprio(1);
    #pragma unroll
    for (int m = 0; m < 8; ++m)
      #pragma unroll
      for (int n = 0; n < 4; ++n) {
        acc[m][n] = __builtin_amdgcn_mfma_f32_16x16x32_bf16(av[m][0], bv[n][0], acc[m][n], 0, 0, 0);
        acc[m][n] = __builtin_amdgcn_mfma_f32_16x16x32_bf16(av[m][1], bv[n][1], acc[m][n], 0, 0, 0);
      }
    __builtin_amdgcn_s_setprio(0);
  }

  // epilogue: D row = (lane>>4)*4 + v, col = lane&15  (verified mapping)
  #pragma unroll
  for (int j = 0; j < 4; ++j) {
    const int col = bn + wn * 64 + j * 16 + fr;
    const float bb = bias[col];
    #pragma unroll
    for (int i = 0; i < 8; ++i) {
      const int row = bm + wm * 128 + i * 16 + g4 * 4;
      #pragma unroll
      for (int v = 0; v < 4; ++v)
        C[(size_t)(row + v) * N + col] = f2bf(acc[i][j][v] + bb);
    }
  }
}

// ---------------- scan: elementwise recurrence over t ----------------
template <int OUT_BF16>
__global__ void scan_kernel(const u16* __restrict__ gates,   // [T*B][3H] bf16
                            const float* __restrict__ h0,    // [B][H]
                            const int* __restrict__ L,       // [B]
                            u16* __restrict__ out_bf,        // [T*B][H] bf16
                            float* __restrict__ out_f,       // [T*B][H] f32
                            float* __restrict__ hlast) {     // [B][H]
  const int e = blockIdx.x * blockDim.x + threadIdx.x;       // 0..B*H-1
  const int b = e >> 10;
  const int j = e & 1023;
  float h = h0[e];
  const int Lb = L[b];
  const size_t g0 = (size_t)b * G3 + j;
  const size_t o0 = (size_t)b * H_DIM + j;
  int t = 0;
  #pragma unroll 8
  for (; t < Lb; ++t) {
    const size_t gt = g0 + (size_t)t * (B_DIM * G3);
    float p = bf2f(gates[gt]);
    float q = bf2f(gates[gt + H_DIM]);
    float r = bf2f(gates[gt + 2 * H_DIM]);
    float ii = 1.f / (1.f + __expf(-(p + h)));
    float ff = 1.f / (1.f + __expf(-(q - h)));
    float u  = ii * r + ff * h;
    float e2 = __expf(2.f * u);
    h = 1.f - 2.f / (e2 + 1.f);                 // tanh(u)
    if (OUT_BF16) out_bf[o0 + (size_t)t * (B_DIM * H_DIM)] = f2bf(h);
    else          out_f [o0 + (size_t)t * (B_DIM * H_DIM)] = h;
  }
  const u16 hb = f2bf(h);
  for (; t < T_DIM; ++t) {                      // frozen tail: stores only
    if (OUT_BF16) out_bf[o0 + (size_t)t * (B_DIM * H_DIM)] = hb;
    else          out_f [o0 + (size_t)t * (B_DIM * H_DIM)] = h;
  }
  hlast[o0] = h;
}

extern "C" void kernel_launch(void* const* d_in, const int* in_sizes, int n_in,
                              void* d_out, int out_size, void* d_ws, size_t ws_size,
                              hipStream_t stream) {
  const float* x  = (const float*)d_in[0];
  const float* h0 = (const float*)d_in[1];
  const float* W1 = (const float*)d_in[2];
  const float* b1 = (const float*)d_in[3];
  const float* W2 = (const float*)d_in[4];
  const float* b2 = (const float*)d_in[5];
  const int*   L  = (const int*)d_in[6];

  float* out2 = (float*)d_out;                         // [T][B][H]
  float* hl   = out2 + (size_t)T_DIM * B_DIM * H_DIM;  // h1 [B][H], then h2

  // workspace layout
  char* w = (char*)d_ws;
  u16* xb    = (u16*)(w);                            //  64 MB  x bf16
  u16* W1t   = (u16*)(w + (size_t)67108864);         //   6 MB  W1^T bf16
  u16* W2t   = (u16*)(w + (size_t)73400320);         //   6 MB  W2^T bf16
  u16* gates = (u16*)(w + (size_t)79691776);         // 192 MB  gates bf16 (reused)
  u16* out1  = (u16*)(w + (size_t)281018368);        //  64 MB  out1 bf16

  cast_f32_to_bf16_kernel<<<2048, 256, 0, stream>>>(x, xb, (T_DIM * B_DIM * I_DIM) / 8);
  dim3 tb(32, 8);
  transpose_cast_kernel<<<dim3(G3 / 32, I_DIM / 32), tb, 0, stream>>>(W1, W1t, I_DIM, G3);
  transpose_cast_kernel<<<dim3(G3 / 32, H_DIM / 32), tb, 0, stream>>>(W2, W2t, H_DIM, G3);

  // layer 1
  gemm256_kernel<<<dim3(G3 / 256, M_DIM / 256), 512, 0, stream>>>(
      xb, W1t, b1, gates, G3);
  scan_kernel<1><<<(B_DIM * H_DIM) / 256, 256, 0, stream>>>(
      gates, h0, L, out1, nullptr, hl);

  // layer 2
  gemm256_kernel<<<dim3(G3 / 256, M_DIM / 256), 512, 0, stream>>>(
      out1, W2t, b2, gates, G3);
  scan_kernel<0><<<(B_DIM * H_DIM) / 256, 256, 0, stream>>>(
      gates, h0 + B_DIM * H_DIM, L, nullptr, out2, hl + B_DIM * H_DIM);
}

// Round 4
// 717.624 us; speedup vs baseline: 1.2032x; 1.2032x over previous
//
#include <hip/hip_runtime.h>

#define T_DIM 512
#define B_DIM 64
#define I_DIM 1024
#define H_DIM 1024
#define G3    3072                 // 3*H
#define M_DIM (T_DIM * B_DIM)      // 32768
#define K_DIM 1024
#define KT    16                   // K_DIM / 64

typedef unsigned short u16;
typedef __bf16 bf16x8 __attribute__((ext_vector_type(8)));
typedef float  f32x4  __attribute__((ext_vector_type(4)));
typedef unsigned short u16x8 __attribute__((ext_vector_type(8)));

__device__ __forceinline__ u16 f2bf(float x) {
  union { float f; unsigned u; } v; v.f = x;
  unsigned r = v.u + 0x7fffu + ((v.u >> 16) & 1u);   // RNE
  return (u16)(r >> 16);
}
__device__ __forceinline__ float bf2f(u16 x) {
  union { unsigned u; float f; } v; v.u = ((unsigned)x) << 16;
  return v.f;
}

// ---------------- cast x: f32 -> bf16, 8 elems/thread ----------------
__global__ void cast_f32_to_bf16_kernel(const float* __restrict__ in,
                                        u16* __restrict__ out, int n8) {
  int idx = blockIdx.x * blockDim.x + threadIdx.x;
  int stride = gridDim.x * blockDim.x;
  for (int i = idx; i < n8; i += stride) {
    const float4* p = (const float4*)in + 2 * (size_t)i;
    float4 a = p[0], b = p[1];
    u16x8 o;
    o[0] = f2bf(a.x); o[1] = f2bf(a.y); o[2] = f2bf(a.z); o[3] = f2bf(a.w);
    o[4] = f2bf(b.x); o[5] = f2bf(b.y); o[6] = f2bf(b.z); o[7] = f2bf(b.w);
    *((u16x8*)out + i) = o;
  }
}

// ------------- transpose-cast W[K][N] f32 -> Wt[N][K] bf16 -------------
__global__ void transpose_cast_kernel(const float* __restrict__ W,
                                      u16* __restrict__ Wt, int K, int N) {
  __shared__ float tile[32][33];
  int n0 = blockIdx.x * 32, k0 = blockIdx.y * 32;
  int tx = threadIdx.x, ty = threadIdx.y;   // blockDim = (32,8)
  #pragma unroll
  for (int dy = 0; dy < 32; dy += 8)
    tile[ty + dy][tx] = W[(size_t)(k0 + ty + dy) * N + n0 + tx];
  __syncthreads();
  #pragma unroll
  for (int dy = 0; dy < 32; dy += 8)
    Wt[(size_t)(n0 + ty + dy) * K + k0 + tx] = f2bf(tile[tx][ty + dy]);
}

// ============ 256x256 GEMM, 4-phase/K-tile, counted vmcnt(6) ============
__device__ __forceinline__ void gload_lds16(const void* g, void* l) {
  __builtin_amdgcn_global_load_lds(
      (const __attribute__((address_space(1))) void*)g,
      (__attribute__((address_space(3))) void*)l, 16, 0, 0);
}

// stage one half-tile (128 rows x 64 k), rows [rb, rb+128) at k0 into lbuf
// (linear [256][64] u16). Source pre-swizzled: LDS[row][c] = G[row][c ^ (row&7)].
__device__ __forceinline__ void stage_half(const u16* __restrict__ G, u16* lbuf,
                                           int rb, int k0, int w, int l) {
  const int cs   = (l & 7) ^ (l >> 3);   // source chunk for this lane
  const int rsub = l >> 3;
  #pragma unroll
  for (int r = 0; r < 2; ++r) {
    const int row0 = rb + r * 64 + w * 8;           // wave-uniform row base (mult of 8)
    gload_lds16(G + (size_t)(row0 + rsub) * K_DIM + k0 + cs * 8,
                lbuf + (size_t)row0 * 64);
  }
}

// read one MFMA fragment; row = (mult of 16) + fr so row&7 == fr&7
__device__ __forceinline__ bf16x8 ldfrag(const u16* buf, int row, int ks, int fr, int g4) {
  const int slot = ((ks << 2) + g4) ^ (fr & 7);
  return *(const bf16x8*)(buf + (size_t)row * 64 + slot * 8);
}

#define BARRIER()  do { __builtin_amdgcn_s_barrier(); __builtin_amdgcn_sched_barrier(0); } while (0)
#define LGKM0()    do { asm volatile("s_waitcnt lgkmcnt(0)" ::: "memory"); __builtin_amdgcn_sched_barrier(0); } while (0)

__global__ __launch_bounds__(512, 2) void gemm256_kernel(
    const u16* __restrict__ A, const u16* __restrict__ Bt,
    const float* __restrict__ bias, u16* __restrict__ C, int N) {
  __shared__ u16 As[2][256 * 64];
  __shared__ u16 Bs[2][256 * 64];
  const int tid = threadIdx.x;
  const int l  = tid & 63, w = tid >> 6;
  const int wm = w >> 2,  wn = w & 3;
  const int fr = l & 15,  g4 = l >> 4;

  // T1: bijective XCD swizzle (nwg = 1536, divisible by 8)
  const int lin = blockIdx.y * gridDim.x + blockIdx.x;
  const int cpx = (gridDim.x * gridDim.y) >> 3;
  const int swz = (lin & 7) * cpx + (lin >> 3);
  const int bx = swz % gridDim.x, by = swz / gridDim.x;
  const int bm = by * 256, bn = bx * 256;

  const u16* Ab = A  + (size_t)bm * K_DIM;
  const u16* Bb = Bt + (size_t)bn * K_DIM;

  // prologue: tile0 fully + tile1 {A-lo, A-hi, B-lo}  (14 loads/thread)
  stage_half(Ab, As[0], 0,   0,  w, l);
  stage_half(Ab, As[0], 128, 0,  w, l);
  stage_half(Bb, Bs[0], 0,   0,  w, l);
  stage_half(Bb, Bs[0], 128, 0,  w, l);
  stage_half(Ab, As[1], 0,   64, w, l);
  stage_half(Ab, As[1], 128, 64, w, l);
  stage_half(Bb, Bs[1], 0,   64, w, l);

  f32x4 acc[8][4] = {};
  bf16x8 av[8][2], bv[4][2];

  // ---- main loop: tiles 0..KT-2; steady-state stages lead by 3 half-tiles ----
  for (int T = 0; T < KT - 1; ++T) {
    const u16* Ac = As[T & 1];
    const u16* Bc = Bs[T & 1];
    u16* An1 = As[(T + 1) & 1];  u16* Bn1 = Bs[(T + 1) & 1];
    u16* An2 = As[T & 1];        u16* Bn2 = Bs[T & 1];   // tile T+2 parity == T
    const int k1 = (T + 1) * 64, k2 = (T + 2) * 64;
    const bool st2 = (T + 2) < KT;

    // tile boundary: drain everything except the newest 3 half-tiles (tile T+1)
    asm volatile("s_waitcnt vmcnt(6)" ::: "memory");
    BARRIER();                      // all waves: tile T fully resident in LDS

    // ---- phase 0: read av[0..3], bv[0..1]; stage B-hi(T+1); MFMA (m0-3, n0-1)
    #pragma unroll
    for (int m = 0; m < 4; ++m) {
      av[m][0] = ldfrag(Ac, wm * 128 + m * 16 + fr, 0, fr, g4);
      av[m][1] = ldfrag(Ac, wm * 128 + m * 16 + fr, 1, fr, g4);
    }
    #pragma unroll
    for (int n = 0; n < 2; ++n) {
      bv[n][0] = ldfrag(Bc, wn * 64 + n * 16 + fr, 0, fr, g4);
      bv[n][1] = ldfrag(Bc, wn * 64 + n * 16 + fr, 1, fr, g4);
    }
    stage_half(Bb, Bn1, 128, k1, w, l);
    BARRIER();
    LGKM0();
    __builtin_amdgcn_s_setprio(1);
    #pragma unroll
    for (int m = 0; m < 4; ++m)
      #pragma unroll
      for (int n = 0; n < 2; ++n) {
        acc[m][n] = __builtin_amdgcn_mfma_f32_16x16x32_bf16(av[m][0], bv[n][0], acc[m][n], 0, 0, 0);
        acc[m][n] = __builtin_amdgcn_mfma_f32_16x16x32_bf16(av[m][1], bv[n][1], acc[m][n], 0, 0, 0);
      }
    __builtin_amdgcn_s_setprio(0);
    BARRIER();

    // ---- phase 1: read av[4..7], bv[2..3]; MFMA (m4-7, n2-3)
    #pragma unroll
    for (int m = 4; m < 8; ++m) {
      av[m][0] = ldfrag(Ac, wm * 128 + m * 16 + fr, 0, fr, g4);
      av[m][1] = ldfrag(Ac, wm * 128 + m * 16 + fr, 1, fr, g4);
    }
    #pragma unroll
    for (int n = 2; n < 4; ++n) {
      bv[n][0] = ldfrag(Bc, wn * 64 + n * 16 + fr, 0, fr, g4);
      bv[n][1] = ldfrag(Bc, wn * 64 + n * 16 + fr, 1, fr, g4);
    }
    BARRIER();
    LGKM0();
    __builtin_amdgcn_s_setprio(1);
    #pragma unroll
    for (int m = 4; m < 8; ++m)
      #pragma unroll
      for (int n = 2; n < 4; ++n) {
        acc[m][n] = __builtin_amdgcn_mfma_f32_16x16x32_bf16(av[m][0], bv[n][0], acc[m][n], 0, 0, 0);
        acc[m][n] = __builtin_amdgcn_mfma_f32_16x16x32_bf16(av[m][1], bv[n][1], acc[m][n], 0, 0, 0);
      }
    __builtin_amdgcn_s_setprio(0);
    BARRIER();

    // ---- phase 2: stage A-lo(T+2); MFMA (m0-3, n2-3)   [A reads of tile T done]
    if (st2) stage_half(Ab, An2, 0, k2, w, l);
    BARRIER();
    __builtin_amdgcn_s_setprio(1);
    #pragma unroll
    for (int m = 0; m < 4; ++m)
      #pragma unroll
      for (int n = 2; n < 4; ++n) {
        acc[m][n] = __builtin_amdgcn_mfma_f32_16x16x32_bf16(av[m][0], bv[n][0], acc[m][n], 0, 0, 0);
        acc[m][n] = __builtin_amdgcn_mfma_f32_16x16x32_bf16(av[m][1], bv[n][1], acc[m][n], 0, 0, 0);
      }
    __builtin_amdgcn_s_setprio(0);
    BARRIER();

    // ---- phase 3: stage A-hi(T+2) + B-lo(T+2); MFMA (m4-7, n0-1)
    if (st2) { stage_half(Ab, An2, 128, k2, w, l); stage_half(Bb, Bn2, 0, k2, w, l); }
    BARRIER();
    __builtin_amdgcn_s_setprio(1);
    #pragma unroll
    for (int m = 4; m < 8; ++m)
      #pragma unroll
      for (int n = 0; n < 2; ++n) {
        acc[m][n] = __builtin_amdgcn_mfma_f32_16x16x32_bf16(av[m][0], bv[n][0], acc[m][n], 0, 0, 0);
        acc[m][n] = __builtin_amdgcn_mfma_f32_16x16x32_bf16(av[m][1], bv[n][1], acc[m][n], 0, 0, 0);
      }
    __builtin_amdgcn_s_setprio(0);
    BARRIER();
  }

  // ---- peeled final tile (T = KT-1): full drain, no staging ----
  {
    const u16* Ac = As[(KT - 1) & 1];
    const u16* Bc = Bs[(KT - 1) & 1];
    asm volatile("s_waitcnt vmcnt(0)" ::: "memory");
    BARRIER();
    #pragma unroll
    for (int m = 0; m < 8; ++m) {
      av[m][0] = ldfrag(Ac, wm * 128 + m * 16 + fr, 0, fr, g4);
      av[m][1] = ldfrag(Ac, wm * 128 + m * 16 + fr, 1, fr, g4);
    }
    #pragma unroll
    for (int n = 0; n < 4; ++n) {
      bv[n][0] = ldfrag(Bc, wn * 64 + n * 16 + fr, 0, fr, g4);
      bv[n][1] = ldfrag(Bc, wn * 64 + n * 16 + fr, 1, fr, g4);
    }
    LGKM0();
    __builtin_amdgcn_s_setprio(1);
    #pragma unroll
    for (int m = 0; m < 8; ++m)
      #pragma unroll
      for (int n = 0; n < 4; ++n) {
        acc[m][n] = __builtin_amdgcn_mfma_f32_16x16x32_bf16(av[m][0], bv[n][0], acc[m][n], 0, 0, 0);
        acc[m][n] = __builtin_amdgcn_mfma_f32_16x16x32_bf16(av[m][1], bv[n][1], acc[m][n], 0, 0, 0);
      }
    __builtin_amdgcn_s_setprio(0);
    BARRIER();                       // all LDS reads done; vmem drained
  }

  // ---- epilogue: per-wave LDS bounce -> fully coalesced 16B stores ----
  float bb[4];
  #pragma unroll
  for (int j = 0; j < 4; ++j) bb[j] = bias[bn + wn * 64 + j * 16 + fr];

  u16* eb = (w < 4) ? ((u16*)As + (size_t)w * 8192)
                    : ((u16*)Bs + (size_t)(w - 4) * 8192);   // private 128x64 region
  #pragma unroll
  for (int i = 0; i < 8; ++i)
    #pragma unroll
    for (int j = 0; j < 4; ++j)
      #pragma unroll
      for (int v = 0; v < 4; ++v) {
        const int row = i * 16 + g4 * 4 + v;
        const int col = j * 16 + fr;
        eb[row * 64 + (col ^ ((row & 12) << 2))] = f2bf(acc[i][j][v] + bb[j]);
      }
  LGKM0();                            // own-wave ds_writes visible (private region)
  #pragma unroll
  for (int c = 0; c < 16; ++c) {
    const int lrow = c * 8 + (l >> 3);
    const int lcol = (l & 7) * 8;
    u16x8 d = *(const u16x8*)&eb[lrow * 64 + (lcol ^ ((lrow & 12) << 2))];
    *(u16x8*)&C[(size_t)(bm + wm * 128 + lrow) * N + (bn + wn * 64 + lcol)] = d;
  }
}

// ---------------- scan: elementwise recurrence over t ----------------
template <int OUT_BF16>
__global__ void scan_kernel(const u16* __restrict__ gates,   // [T*B][3H] bf16
                            const float* __restrict__ h0,    // [B][H]
                            const int* __restrict__ L,       // [B]
                            u16* __restrict__ out_bf,        // [T*B][H] bf16
                            float* __restrict__ out_f,       // [T*B][H] f32
                            float* __restrict__ hlast) {     // [B][H]
  const int e = blockIdx.x * blockDim.x + threadIdx.x;       // 0..B*H-1
  const int b = e >> 10;
  const int j = e & 1023;
  float h = h0[e];
  const int Lb = L[b];
  const size_t g0 = (size_t)b * G3 + j;
  const size_t o0 = (size_t)b * H_DIM + j;
  int t = 0;
  #pragma unroll 8
  for (; t < Lb; ++t) {
    const size_t gt = g0 + (size_t)t * (B_DIM * G3);
    float p = bf2f(gates[gt]);
    float q = bf2f(gates[gt + H_DIM]);
    float r = bf2f(gates[gt + 2 * H_DIM]);
    float ii = 1.f / (1.f + __expf(-(p + h)));
    float ff = 1.f / (1.f + __expf(-(q - h)));
    float u  = ii * r + ff * h;
    float e2 = __expf(2.f * u);
    h = 1.f - 2.f / (e2 + 1.f);                 // tanh(u)
    if (OUT_BF16) out_bf[o0 + (size_t)t * (B_DIM * H_DIM)] = f2bf(h);
    else          out_f [o0 + (size_t)t * (B_DIM * H_DIM)] = h;
  }
  const u16 hb = f2bf(h);
  for (; t < T_DIM; ++t) {                      // frozen tail: stores only
    if (OUT_BF16) out_bf[o0 + (size_t)t * (B_DIM * H_DIM)] = hb;
    else          out_f [o0 + (size_t)t * (B_DIM * H_DIM)] = h;
  }
  hlast[o0] = h;
}

extern "C" void kernel_launch(void* const* d_in, const int* in_sizes, int n_in,
                              void* d_out, int out_size, void* d_ws, size_t ws_size,
                              hipStream_t stream) {
  const float* x  = (const float*)d_in[0];
  const float* h0 = (const float*)d_in[1];
  const float* W1 = (const float*)d_in[2];
  const float* b1 = (const float*)d_in[3];
  const float* W2 = (const float*)d_in[4];
  const float* b2 = (const float*)d_in[5];
  const int*   L  = (const int*)d_in[6];

  float* out2 = (float*)d_out;                         // [T][B][H]
  float* hl   = out2 + (size_t)T_DIM * B_DIM * H_DIM;  // h1 [B][H], then h2

  // workspace layout
  char* w = (char*)d_ws;
  u16* xb    = (u16*)(w);                            //  64 MB  x bf16
  u16* W1t   = (u16*)(w + (size_t)67108864);         //   6 MB  W1^T bf16
  u16* W2t   = (u16*)(w + (size_t)73400320);         //   6 MB  W2^T bf16
  u16* gates = (u16*)(w + (size_t)79691776);         // 192 MB  gates bf16 (reused)
  u16* out1  = (u16*)(w + (size_t)281018368);        //  64 MB  out1 bf16

  cast_f32_to_bf16_kernel<<<2048, 256, 0, stream>>>(x, xb, (T_DIM * B_DIM * I_DIM) / 8);
  dim3 tb(32, 8);
  transpose_cast_kernel<<<dim3(G3 / 32, I_DIM / 32), tb, 0, stream>>>(W1, W1t, I_DIM, G3);
  transpose_cast_kernel<<<dim3(G3 / 32, H_DIM / 32), tb, 0, stream>>>(W2, W2t, H_DIM, G3);

  // layer 1
  gemm256_kernel<<<dim3(G3 / 256, M_DIM / 256), 512, 0, stream>>>(
      xb, W1t, b1, gates, G3);
  scan_kernel<1><<<(B_DIM * H_DIM) / 256, 256, 0, stream>>>(
      gates, h0, L, out1, nullptr, hl);

  // layer 2
  gemm256_kernel<<<dim3(G3 / 256, M_DIM / 256), 512, 0, stream>>>(
      out1, W2t, b2, gates, G3);
  scan_kernel<0><<<(B_DIM * H_DIM) / 256, 256, 0, stream>>>(
      gates, h0 + B_DIM * H_DIM, L, nullptr, out2, hl + B_DIM * H_DIM);
}

// Round 5
// 672.990 us; speedup vs baseline: 1.2830x; 1.0663x over previous
//
#include <hip/hip_runtime.h>

#define T_DIM 512
#define B_DIM 64
#define I_DIM 1024
#define H_DIM 1024
#define G3    3072                 // 3*H
#define M_DIM (T_DIM * B_DIM)      // 32768
#define K_DIM 1024
#define KT    16                   // K_DIM / 64

typedef unsigned short u16;
typedef __bf16 bf16x8 __attribute__((ext_vector_type(8)));
typedef float  f32x4  __attribute__((ext_vector_type(4)));
typedef unsigned short u16x8 __attribute__((ext_vector_type(8)));

__device__ __forceinline__ u16 f2bf(float x) {
  union { float f; unsigned u; } v; v.f = x;
  unsigned r = v.u + 0x7fffu + ((v.u >> 16) & 1u);   // RNE
  return (u16)(r >> 16);
}
__device__ __forceinline__ float bf2f(u16 x) {
  union { unsigned u; float f; } v; v.u = ((unsigned)x) << 16;
  return v.f;
}

// ---------------- cast x: f32 -> bf16, 8 elems/thread ----------------
__global__ void cast_f32_to_bf16_kernel(const float* __restrict__ in,
                                        u16* __restrict__ out, int n8) {
  int idx = blockIdx.x * blockDim.x + threadIdx.x;
  int stride = gridDim.x * blockDim.x;
  for (int i = idx; i < n8; i += stride) {
    const float4* p = (const float4*)in + 2 * (size_t)i;
    float4 a = p[0], b = p[1];
    u16x8 o;
    o[0] = f2bf(a.x); o[1] = f2bf(a.y); o[2] = f2bf(a.z); o[3] = f2bf(a.w);
    o[4] = f2bf(b.x); o[5] = f2bf(b.y); o[6] = f2bf(b.z); o[7] = f2bf(b.w);
    *((u16x8*)out + i) = o;
  }
}

// ------------- transpose-cast W[K][N] f32 -> Wt[N][K] bf16 -------------
__global__ void transpose_cast_kernel(const float* __restrict__ W,
                                      u16* __restrict__ Wt, int K, int N) {
  __shared__ float tile[32][33];
  int n0 = blockIdx.x * 32, k0 = blockIdx.y * 32;
  int tx = threadIdx.x, ty = threadIdx.y;   // blockDim = (32,8)
  #pragma unroll
  for (int dy = 0; dy < 32; dy += 8)
    tile[ty + dy][tx] = W[(size_t)(k0 + ty + dy) * N + n0 + tx];
  __syncthreads();
  #pragma unroll
  for (int dy = 0; dy < 32; dy += 8)
    Wt[(size_t)(n0 + ty + dy) * K + k0 + tx] = f2bf(tile[tx][ty + dy]);
}

// ====== 256x256 GEMM, 2 barriers/K-tile, MFMA-overlapped ds_reads ======
__device__ __forceinline__ void gload_lds16(const void* g, void* l) {
  __builtin_amdgcn_global_load_lds(
      (const __attribute__((address_space(1))) void*)g,
      (__attribute__((address_space(3))) void*)l, 16, 0, 0);
}

// stage one half-tile (128 rows x 64 k), rows [rb, rb+128) at k0 into lbuf
// (linear [256][64] u16). Source pre-swizzled: LDS[row][c] = G[row][c ^ (row&7)].
__device__ __forceinline__ void stage_half(const u16* __restrict__ G, u16* lbuf,
                                           int rb, int k0, int w, int l) {
  const int cs   = (l & 7) ^ (l >> 3);   // source chunk for this lane
  const int rsub = l >> 3;
  #pragma unroll
  for (int r = 0; r < 2; ++r) {
    const int row0 = rb + r * 64 + w * 8;           // wave-uniform row base (mult of 8)
    gload_lds16(G + (size_t)(row0 + rsub) * K_DIM + k0 + cs * 8,
                lbuf + (size_t)row0 * 64);
  }
}

// read one MFMA fragment; row = (mult of 16) + fr so row&7 == fr&7
__device__ __forceinline__ bf16x8 ldfrag(const u16* buf, int row, int ks, int fr, int g4) {
  const int slot = ((ks << 2) + g4) ^ (fr & 7);
  return *(const bf16x8*)(buf + (size_t)row * 64 + slot * 8);
}

#define BARRIER()  do { __builtin_amdgcn_s_barrier(); __builtin_amdgcn_sched_barrier(0); } while (0)
#define LGKM0()    do { asm volatile("s_waitcnt lgkmcnt(0)" ::: "memory"); __builtin_amdgcn_sched_barrier(0); } while (0)

#define MFMA_Q(ACC, AV, BV)                                                            \
  do {                                                                                 \
    __builtin_amdgcn_s_setprio(1);                                                     \
    _Pragma("unroll")                                                                  \
    for (int m = 0; m < 4; ++m)                                                        \
      _Pragma("unroll")                                                                \
      for (int n = 0; n < 2; ++n) {                                                    \
        ACC = __builtin_amdgcn_mfma_f32_16x16x32_bf16(AV[m][0], BV[n][0], ACC, 0, 0, 0); \
        ACC = __builtin_amdgcn_mfma_f32_16x16x32_bf16(AV[m][1], BV[n][1], ACC, 0, 0, 0); \
      }                                                                                \
    __builtin_amdgcn_s_setprio(0);                                                     \
  } while (0)

__global__ __launch_bounds__(512, 2) void gemm256_kernel(
    const u16* __restrict__ A, const u16* __restrict__ Bt,
    const float* __restrict__ bias, u16* __restrict__ C, int N) {
  __shared__ u16 As[2][256 * 64];
  __shared__ u16 Bs[2][256 * 64];
  const int tid = threadIdx.x;
  const int l  = tid & 63, w = tid >> 6;
  const int wm = w >> 2,  wn = w & 3;
  const int fr = l & 15,  g4 = l >> 4;

  // T1: bijective XCD swizzle (nwg = 1536, divisible by 8)
  const int lin = blockIdx.y * gridDim.x + blockIdx.x;
  const int cpx = (gridDim.x * gridDim.y) >> 3;
  const int swz = (lin & 7) * cpx + (lin >> 3);
  const int bx = swz % gridDim.x, by = swz / gridDim.x;
  const int bm = by * 256, bn = bx * 256;

  const u16* Ab = A  + (size_t)bm * K_DIM;
  const u16* Bb = Bt + (size_t)bn * K_DIM;

  // prologue: tile0 fully + tile1 {A-lo, A-hi, B-lo}  (14 loads/thread)
  stage_half(Ab, As[0], 0,   0,  w, l);
  stage_half(Ab, As[0], 128, 0,  w, l);
  stage_half(Bb, Bs[0], 0,   0,  w, l);
  stage_half(Bb, Bs[0], 128, 0,  w, l);
  stage_half(Ab, As[1], 0,   64, w, l);
  stage_half(Ab, As[1], 128, 64, w, l);
  stage_half(Bb, Bs[1], 0,   64, w, l);

  f32x4 acc[8][4] = {};
  bf16x8 av0[4][2], av1[4][2], bv0[2][2], bv1[2][2];

  // ---- main loop: tiles 0..KT-2 ----
  for (int T = 0; T < KT - 1; ++T) {
    const u16* Ac = As[T & 1];
    const u16* Bc = Bs[T & 1];
    u16* Bn1 = Bs[(T + 1) & 1];
    u16* An2 = As[T & 1];        u16* Bn2 = Bs[T & 1];   // tile T+2 parity == T
    const int k1 = (T + 1) * 64, k2 = (T + 2) * 64;
    const bool st2 = (T + 2) < KT;

    // tile top: tile T's newest-needed loads are >= 1 full tile old -> cheap
    asm volatile("s_waitcnt vmcnt(6)" ::: "memory");
    BARRIER();                     // tile T resident; tile T-1 reads all consumed

    // reads for Q0 (av0, bv0) + stage B-hi(T+1)
    #pragma unroll
    for (int m = 0; m < 4; ++m) {
      av0[m][0] = ldfrag(Ac, wm * 128 + m * 16 + fr, 0, fr, g4);
      av0[m][1] = ldfrag(Ac, wm * 128 + m * 16 + fr, 1, fr, g4);
    }
    #pragma unroll
    for (int n = 0; n < 2; ++n) {
      bv0[n][0] = ldfrag(Bc, wn * 64 + n * 16 + fr, 0, fr, g4);
      bv0[n][1] = ldfrag(Bc, wn * 64 + n * 16 + fr, 1, fr, g4);
    }
    stage_half(Bb, Bn1, 128, k1, w, l);
    LGKM0();

    // Q0 (m0-3, n0-1); bv1 reads issue behind the MFMAs -> LDS || matrix
    MFMA_Q(acc[m][n], av0, bv0);
    #pragma unroll
    for (int n = 0; n < 2; ++n) {
      bv1[n][0] = ldfrag(Bc, wn * 64 + (n + 2) * 16 + fr, 0, fr, g4);
      bv1[n][1] = ldfrag(Bc, wn * 64 + (n + 2) * 16 + fr, 1, fr, g4);
    }
    LGKM0();

    // Q1 (m0-3, n2-3); av1 reads issue behind
    MFMA_Q(acc[m][n + 2], av0, bv1);
    #pragma unroll
    for (int m = 0; m < 4; ++m) {
      av1[m][0] = ldfrag(Ac, wm * 128 + (m + 4) * 16 + fr, 0, fr, g4);
      av1[m][1] = ldfrag(Ac, wm * 128 + (m + 4) * 16 + fr, 1, fr, g4);
    }
    LGKM0();
    BARRIER();                     // all waves' tile-T LDS reads complete

    // stage tile T+2 into the just-freed roles of this buffer
    if (st2) {
      stage_half(Ab, An2, 0,   k2, w, l);
      stage_half(Ab, An2, 128, k2, w, l);
      stage_half(Bb, Bn2, 0,   k2, w, l);
    }

    // Q2 (m4-7, n2-3), Q3 (m4-7, n0-1): pure MFMA, stage writes land underneath
    MFMA_Q(acc[m + 4][n + 2], av1, bv1);
    MFMA_Q(acc[m + 4][n],     av1, bv0);
  }

  // ---- peeled final tile (T = KT-1): only B-hi(KT-1) outstanding ----
  {
    const u16* Ac = As[(KT - 1) & 1];
    const u16* Bc = Bs[(KT - 1) & 1];
    asm volatile("s_waitcnt vmcnt(0)" ::: "memory");
    BARRIER();
    #pragma unroll
    for (int m = 0; m < 4; ++m) {
      av0[m][0] = ldfrag(Ac, wm * 128 + m * 16 + fr, 0, fr, g4);
      av0[m][1] = ldfrag(Ac, wm * 128 + m * 16 + fr, 1, fr, g4);
      av1[m][0] = ldfrag(Ac, wm * 128 + (m + 4) * 16 + fr, 0, fr, g4);
      av1[m][1] = ldfrag(Ac, wm * 128 + (m + 4) * 16 + fr, 1, fr, g4);
    }
    #pragma unroll
    for (int n = 0; n < 2; ++n) {
      bv0[n][0] = ldfrag(Bc, wn * 64 + n * 16 + fr, 0, fr, g4);
      bv0[n][1] = ldfrag(Bc, wn * 64 + n * 16 + fr, 1, fr, g4);
      bv1[n][0] = ldfrag(Bc, wn * 64 + (n + 2) * 16 + fr, 0, fr, g4);
      bv1[n][1] = ldfrag(Bc, wn * 64 + (n + 2) * 16 + fr, 1, fr, g4);
    }
    LGKM0();
    MFMA_Q(acc[m][n],         av0, bv0);
    MFMA_Q(acc[m][n + 2],     av0, bv1);
    MFMA_Q(acc[m + 4][n + 2], av1, bv1);
    MFMA_Q(acc[m + 4][n],     av1, bv0);
    BARRIER();                     // all LDS reads done -> LDS reusable as scratch
  }

  // ---- epilogue: per-wave LDS bounce -> fully coalesced 16B stores ----
  float bb[4];
  #pragma unroll
  for (int j = 0; j < 4; ++j) bb[j] = bias[bn + wn * 64 + j * 16 + fr];

  u16* eb = (w < 4) ? ((u16*)As + (size_t)w * 8192)
                    : ((u16*)Bs + (size_t)(w - 4) * 8192);   // private 128x64 region
  #pragma unroll
  for (int i = 0; i < 8; ++i)
    #pragma unroll
    for (int j = 0; j < 4; ++j)
      #pragma unroll
      for (int v = 0; v < 4; ++v) {
        const int row = i * 16 + g4 * 4 + v;
        const int col = j * 16 + fr;
        eb[row * 64 + (col ^ ((row & 12) << 2))] = f2bf(acc[i][j][v] + bb[j]);
      }
  LGKM0();                            // own-wave ds_writes visible (private region)
  #pragma unroll
  for (int c = 0; c < 16; ++c) {
    const int lrow = c * 8 + (l >> 3);
    const int lcol = (l & 7) * 8;
    u16x8 d = *(const u16x8*)&eb[lrow * 64 + (lcol ^ ((lrow & 12) << 2))];
    *(u16x8*)&C[(size_t)(bm + wm * 128 + lrow) * N + (bn + wn * 64 + lcol)] = d;
  }
}

// ---------------- scan: elementwise recurrence over t ----------------
template <int OUT_BF16>
__global__ void scan_kernel(const u16* __restrict__ gates,   // [T*B][3H] bf16
                            const float* __restrict__ h0,    // [B][H]
                            const int* __restrict__ L,       // [B]
                            u16* __restrict__ out_bf,        // [T*B][H] bf16
                            float* __restrict__ out_f,       // [T*B][H] f32
                            float* __restrict__ hlast) {     // [B][H]
  const int e = blockIdx.x * blockDim.x + threadIdx.x;       // 0..B*H-1
  const int b = e >> 10;
  const int j = e & 1023;
  float h = h0[e];
  const int Lb = L[b];
  const size_t g0 = (size_t)b * G3 + j;
  const size_t o0 = (size_t)b * H_DIM + j;
  int t = 0;
  #pragma unroll 8
  for (; t < Lb; ++t) {
    const size_t gt = g0 + (size_t)t * (B_DIM * G3);
    float p = bf2f(gates[gt]);
    float q = bf2f(gates[gt + H_DIM]);
    float r = bf2f(gates[gt + 2 * H_DIM]);
    float ii = 1.f / (1.f + __expf(-(p + h)));
    float ff = 1.f / (1.f + __expf(-(q - h)));
    float u  = ii * r + ff * h;
    float e2 = __expf(2.f * u);
    h = 1.f - 2.f / (e2 + 1.f);                 // tanh(u)
    if (OUT_BF16) out_bf[o0 + (size_t)t * (B_DIM * H_DIM)] = f2bf(h);
    else          out_f [o0 + (size_t)t * (B_DIM * H_DIM)] = h;
  }
  const u16 hb = f2bf(h);
  for (; t < T_DIM; ++t) {                      // frozen tail: stores only
    if (OUT_BF16) out_bf[o0 + (size_t)t * (B_DIM * H_DIM)] = hb;
    else          out_f [o0 + (size_t)t * (B_DIM * H_DIM)] = h;
  }
  hlast[o0] = h;
}

extern "C" void kernel_launch(void* const* d_in, const int* in_sizes, int n_in,
                              void* d_out, int out_size, void* d_ws, size_t ws_size,
                              hipStream_t stream) {
  const float* x  = (const float*)d_in[0];
  const float* h0 = (const float*)d_in[1];
  const float* W1 = (const float*)d_in[2];
  const float* b1 = (const float*)d_in[3];
  const float* W2 = (const float*)d_in[4];
  const float* b2 = (const float*)d_in[5];
  const int*   L  = (const int*)d_in[6];

  float* out2 = (float*)d_out;                         // [T][B][H]
  float* hl   = out2 + (size_t)T_DIM * B_DIM * H_DIM;  // h1 [B][H], then h2

  // workspace layout
  char* w = (char*)d_ws;
  u16* xb    = (u16*)(w);                            //  64 MB  x bf16
  u16* W1t   = (u16*)(w + (size_t)67108864);         //   6 MB  W1^T bf16
  u16* W2t   = (u16*)(w + (size_t)73400320);         //   6 MB  W2^T bf16
  u16* gates = (u16*)(w + (size_t)79691776);         // 192 MB  gates bf16 (reused)
  u16* out1  = (u16*)(w + (size_t)281018368);        //  64 MB  out1 bf16

  cast_f32_to_bf16_kernel<<<2048, 256, 0, stream>>>(x, xb, (T_DIM * B_DIM * I_DIM) / 8);
  dim3 tb(32, 8);
  transpose_cast_kernel<<<dim3(G3 / 32, I_DIM / 32), tb, 0, stream>>>(W1, W1t, I_DIM, G3);
  transpose_cast_kernel<<<dim3(G3 / 32, H_DIM / 32), tb, 0, stream>>>(W2, W2t, H_DIM, G3);

  // layer 1
  gemm256_kernel<<<dim3(G3 / 256, M_DIM / 256), 512, 0, stream>>>(
      xb, W1t, b1, gates, G3);
  scan_kernel<1><<<(B_DIM * H_DIM) / 256, 256, 0, stream>>>(
      gates, h0, L, out1, nullptr, hl);

  // layer 2
  gemm256_kernel<<<dim3(G3 / 256, M_DIM / 256), 512, 0, stream>>>(
      out1, W2t, b2, gates, G3);
  scan_kernel<0><<<(B_DIM * H_DIM) / 256, 256, 0, stream>>>(
      gates, h0 + B_DIM * H_DIM, L, nullptr, out2, hl + B_DIM * H_DIM);
}